// Round 8
// baseline (122.041 us; speedup 1.0000x reference)
//
#include <hip/hip_runtime.h>

// X-ray forward projection. Volume 128^3 fp32, detector 179x179, 10 views.
// Inputs fp32/int32: I_rec [1,1,128,128,128], poses [50,3], idx [10].
// Output fp32 flat: projections [10,179,179] then idx [10] as float.
//
// Geometry: vol[c][y][a], c = spatial_x+63.5, y index = plane p, a = spatial_z+63.5.
// Sampled y at plane p is exactly p-0.5 => ty=0.5:
//   contribution(p) = 0.5*(bilin(slice p-1) + bilin(slice p)) = 0.5*bilin(PS[p])
// Ray linear in p: c(p)=cb+p*sx, a(p)=ab+p*sz;  weight dxw = dist(Pd,E)/ey.
//
// R6 (kept): PS[p][ci][ai] zero-padded slice-sum volume in d_ws ([128][131][132]
// fp32); clamped unguarded bilinear == reference masked zero-padding.
// R7 post-mortem: 64-thr blocks hit the 16-workgroup/CU cap -> occupancy stuck
// at ~41%, latency-bound at 53us. Binding constraint = total wave parallelism.
//
// R8: split each ray into 2 p-segments, one 256-thread block each
// (grid 2700 -> 10.5 blocks/CU vs the 8-block/32-wave residency cap).
// Segments atomicAdd fp32 partial sums into out; out zero-init + idx tail
// folded into pad_kernel (stream order guarantees pad completes first).

#define DVOL   128
#define RES    179
#define NPROJ  10
#define OUT_PROJ (NPROJ * RES * RES)
#define NSEG   2
#define SEGLEN (DVOL / NSEG)

#define PS_A   132                    // a-stride (1 low pad + 128 + 2 high + 1 align)
#define PS_C   131                    // c rows   (1 low pad + 128 + 2 high)
#define PS_SLAB (PS_C * PS_A)         // 17292 floats per p-slab
#define PS_TOT  (DVOL * PS_SLAB)      // 2,213,376 floats = 8.85 MB

// ---- PS builder + out zero-init + idx tail.
// PS[p][ci][ai] = (p==0 ? v[p] : v[p-1]+v[p]) at (ci-1, ai-1), zero border.
__global__ __launch_bounds__(256) void pad_kernel(const float* __restrict__ vol,
                                                  float* __restrict__ ps,
                                                  const int* __restrict__ idx,
                                                  float* __restrict__ out) {
    const int t = blockIdx.x * 256 + threadIdx.x;
    if (t >= PS_TOT) return;
    if (t < OUT_PROJ) out[t] = 0.0f;                         // zero proj region
    else if (t < OUT_PROJ + NPROJ) out[t] = (float)idx[t - OUT_PROJ];
    const int p  = t / PS_SLAB;
    const int r  = t - p * PS_SLAB;
    const int ci = r / PS_A;
    const int ai = r - ci * PS_A;
    const int c = ci - 1, a = ai - 1;
    float v = 0.0f;
    if (c >= 0 && c < 128 && a >= 0 && a < 128) {
        const float* src = vol + (c << 14) + (p << 7) + a;   // vol[c][p][a]
        v = src[0];
        if (p >= 1) v += src[-128];                          // vol[c][p-1][a]
    }
    ps[t] = v;
}

__device__ __forceinline__ void axis_interval(float base, float slope, float lo, float hi,
                                              float& t0, float& t1) {
    if (fabsf(slope) < 1e-9f) {
        const bool in = (base >= lo && base <= hi);
        t0 = in ? -1e30f : 1e30f;
        t1 = in ?  1e30f : -1e30f;
    } else {
        const float inv = 1.0f / slope;
        const float a = (lo - base) * inv;
        const float b = (hi - base) * inv;
        t0 = fminf(a, b);
        t1 = fmaxf(a, b);
    }
}

__device__ __forceinline__ int wave_imin(int v) {
    #pragma unroll
    for (int o = 32; o; o >>= 1) v = min(v, __shfl_xor(v, o, 64));
    return v;
}
__device__ __forceinline__ int wave_imax(int v) {
    #pragma unroll
    for (int o = 32; o; o >>= 1) v = max(v, __shfl_xor(v, o, 64));
    return v;
}

__global__ __launch_bounds__(256) void proj_fast(
    const float* __restrict__ ps,     // PS [128][131][132]
    const float* __restrict__ poses,  // [50,3]
    const int* __restrict__ idx,      // [10]
    float* __restrict__ out)          // [10,179,179] (+tail, written by pad)
{
    const int lane = threadIdx.x & 63;
    const int wid  = threadIdx.x >> 6;
    int gj = blockIdx.x * 64 + lane;        // detector col -> contiguous a
    int gi = blockIdx.y * 4 + wid;          // detector row (wave-uniform)
    const int zz  = blockIdx.z;
    const int j   = zz >> 1;                // projection
    const int seg = zz & 1;                 // p-segment

    const bool store_ok = (gi < RES) && (gj < RES);
    gi = min(gi, RES - 1);   // stays wave-uniform
    gj = min(gj, RES - 1);   // dup lanes compute duplicates, store masked

    const int pid = idx[j];
    const float ex = poses[pid * 3 + 0];
    const float ey = poses[pid * 3 + 1];    // [256,384)
    const float ez = poses[pid * 3 + 2];

    const float pdx = (float)gi - 89.5f;
    const float pdz = (float)gj - 89.5f;

    const float inv_ey = 1.0f / ey;
    const float sx = (ex - pdx) * inv_ey;   // wave-uniform
    const float sz = (ez - pdz) * inv_ey;   // per-lane
    const float ddx = pdx - ex, ddz = pdz - ez;
    const float dxw = sqrtf(ddx * ddx + ey * ey + ddz * ddz) * fabsf(inv_ey);
    const float cb = pdx + 63.5f;           // wave-uniform
    const float ab = pdz + 63.5f;

    // Guard trim (conservative superset of nonzero steps), wave-uniform.
    float gc0, gc1, ga0, ga1;
    axis_interval(cb, sx, -1.0f, 128.0f, gc0, gc1);
    axis_interval(ab, sz, -1.0f, 128.0f, ga0, ga1);
    const float q_lo = fmaxf(fmaxf(gc0, ga0), 0.0f);
    const float q_hi = fminf(fminf(gc1, ga1), 127.0f);
    int q0, q1;
    if (q_lo <= q_hi + 0.5f) {
        q0 = max(0, (int)ceilf(q_lo) - 1);
        q1 = min(DVOL, (int)floorf(q_hi) + 2);
    } else { q0 = DVOL; q1 = 0; }           // miss lane: neutral for reduce
    int Q0 = wave_imin(q0);
    int Q1 = wave_imax(q1);
    // Intersect with this block's p-segment.
    Q0 = max(Q0, seg * SEGLEN);
    Q1 = min(Q1, seg * SEGLEN + SEGLEN);
    Q0 = __builtin_amdgcn_readfirstlane(Q0);
    Q1 = __builtin_amdgcn_readfirstlane(Q1);
    if (Q0 >= Q1) return;                   // dead segment retires fast

    float acc = 0.0f;
    {
        float cf = fmaf((float)Q0, sx, cb);
        float af = fmaf((float)Q0, sz, ab);
        const float* slab = ps + Q0 * PS_SLAB;
        #pragma unroll 8
        for (int p = Q0; p < Q1; ++p) {
            // clamp to [-1,128]: out-of-guard lanes land on the zero border
            const float cfc = fminf(fmaxf(cf, -1.0f), 128.0f);
            const float afc = fminf(fmaxf(af, -1.0f), 128.0f);
            const float c0f = floorf(cfc);
            const float a0f = floorf(afc);
            const float tc = cfc - c0f;
            const float ta = afc - a0f;
            const int c0 = __builtin_amdgcn_readfirstlane((int)c0f);  // uniform
            const int a0 = (int)a0f;
            const float* row = slab + (c0 + 1) * PS_A + 1;            // scalar base
            const float2 r0 = *(const float2*)(row + a0);
            const float2 r1 = *(const float2*)(row + PS_A + a0);
            const float h0 = fmaf(ta, r0.y - r0.x, r0.x);
            const float h1 = fmaf(ta, r1.y - r1.x, r1.x);
            acc += fmaf(tc, h1 - h0, h0);
            cf += sx; af += sz; slab += PS_SLAB;
        }
    }
    if (store_ok)
        atomicAdd(&out[j * (RES * RES) + gi * RES + gj], acc * (0.5f * dxw));
}

// ---------- fallback (R3-proven, used only if ws too small) ----------
__global__ __launch_bounds__(256) void proj_kernel_fb(
    const float* __restrict__ vol, const float* __restrict__ poses,
    const int* __restrict__ idx, float* __restrict__ out)
{
    const int gj = blockIdx.x * 64 + (threadIdx.x & 63);
    const int gi = blockIdx.y * 4 + (threadIdx.x >> 6);
    const int j  = blockIdx.z;
    if (blockIdx.x == 0 && blockIdx.y == 0 && j == 0 && threadIdx.x < NPROJ)
        out[OUT_PROJ + threadIdx.x] = (float)idx[threadIdx.x];
    if (gi >= RES || gj >= RES) return;
    const int pid = idx[j];
    const float ex = poses[pid*3+0], ey = poses[pid*3+1], ez = poses[pid*3+2];
    const float pdx = (float)gi - 89.5f, pdz = (float)gj - 89.5f;
    const float inv_ey = 1.0f / ey;
    const float sx = (ex - pdx) * inv_ey, sz = (ez - pdz) * inv_ey;
    const float ddx = pdx - ex, ddz = pdz - ez;
    const float dxw = sqrtf(ddx*ddx + ey*ey + ddz*ddz) * fabsf(inv_ey);
    const float cb = pdx + 63.5f, ab = pdz + 63.5f;
    float acc = 0.0f;
    for (int p = 0; p < DVOL; ++p) {
        const float cf = fmaf((float)p, sx, cb);
        const float af = fmaf((float)p, sz, ab);
        if (cf >= -1.0f && cf < 128.0f && af >= -1.0f && af < 128.0f) {
            const float c0f = floorf(cf), a0f = floorf(af);
            const float tc = cf - c0f, ta = af - a0f;
            const int c0 = (int)c0f, a0 = (int)a0f;
            const float wc0 = (c0 >= 0)   ? (1.0f - tc) : 0.0f;
            const float wc1 = (c0 <= 126) ? tc          : 0.0f;
            const float wa0 = (a0 >= 0)   ? (1.0f - ta) : 0.0f;
            const float wa1 = (a0 <= 126) ? ta          : 0.0f;
            const int c0c = c0 < 0 ? 0 : c0;
            const int c1c = c0 >= 127 ? 127 : c0 + 1;
            const int a0c = a0 < 0 ? 0 : a0;
            const int a1c = a0 >= 127 ? 127 : a0 + 1;
            const float w00 = wc0*wa0, w01 = wc0*wa1, w10 = wc1*wa0, w11 = wc1*wa1;
            const int b0 = (c0c << 14) + (p << 7);
            const int b1 = (c1c << 14) + (p << 7);
            float s = w00*vol[b0+a0c] + w01*vol[b0+a1c] + w10*vol[b1+a0c] + w11*vol[b1+a1c];
            if (p >= 1)
                s += w00*vol[b0+a0c-128] + w01*vol[b0+a1c-128]
                   + w10*vol[b1+a0c-128] + w11*vol[b1+a1c-128];
            acc += 0.5f * s;
        }
    }
    out[j * (RES * RES) + gi * RES + gj] = acc * dxw;
}

extern "C" void kernel_launch(void* const* d_in, const int* in_sizes, int n_in,
                              void* d_out, int out_size, void* d_ws, size_t ws_size,
                              hipStream_t stream) {
    const float* vol   = (const float*)d_in[0];
    const float* poses = (const float*)d_in[1];
    const int*   idx   = (const int*)d_in[2];
    float* out = (float*)d_out;

    if (ws_size >= (size_t)PS_TOT * sizeof(float)) {
        float* ps = (float*)d_ws;
        pad_kernel<<<PS_TOT / 256, 256, 0, stream>>>(vol, ps, idx, out);
        dim3 grid(3 /*ceil(179/64)*/, 45 /*ceil(179/4)*/, NPROJ * NSEG);  // 2700 blocks
        proj_fast<<<grid, 256, 0, stream>>>(ps, poses, idx, out);
    } else {
        dim3 grid(3, 45, NPROJ);
        proj_kernel_fb<<<grid, 256, 0, stream>>>(vol, poses, idx, out);
    }
}

// Round 9
// 108.725 us; speedup vs baseline: 1.1225x; 1.1225x over previous
//
#include <hip/hip_runtime.h>

// X-ray forward projection. Volume 128^3 fp32, detector 179x179, 10 views.
// Inputs fp32/int32: I_rec [1,1,128,128,128], poses [50,3], idx [10].
// Output fp32 flat: projections [10,179,179] then idx [10] as float.
//
// Geometry: vol[c][y][a], c = spatial_x+63.5, y index = plane p, a = spatial_z+63.5.
// Sampled y at plane p is exactly p-0.5 => ty=0.5:
//   contribution(p) = 0.5*(bilin(slice p-1) + bilin(slice p)) = 0.5*bilin(PS[p])
// Ray linear in p: c(p)=cb+p*sx, a(p)=ab+p*sz;  weight dxw = dist(Pd,E)/ey.
//
// R6 (kept): PS[p][ci][ai] zero-padded slice-sum volume in d_ws ([128][131][132]
// fp32); clamped unguarded bilinear == reference masked zero-padding.
// R8 post-mortem: ray-splitting + atomics regressed (locality loss, FETCH +25%).
// R9: VGPR=12 in R6-R8 proves the compiler never batched loads (~2 in flight,
// ~400cyc L3 latency exposed per step). Manual 8-step batching with explicit
// register arrays forces 16 loads in flight; 128-thr blocks (2 waves) for
// finer drain granularity. Expect VGPR ~50-64 as the verification signal.

#define DVOL   128
#define RES    179
#define NPROJ  10
#define OUT_PROJ (NPROJ * RES * RES)
#define BATCH  8

#define PS_A   132                    // a-stride (1 low pad + 128 + 2 high + 1 align)
#define PS_C   131                    // c rows   (1 low pad + 128 + 2 high)
#define PS_SLAB (PS_C * PS_A)         // 17292 floats per p-slab
#define PS_TOT  (DVOL * PS_SLAB)      // 2,213,376 floats = 8.85 MB

// ---- PS builder: PS[p][ci][ai] = (p==0 ? v[p] : v[p-1]+v[p]) at (ci-1, ai-1).
__global__ __launch_bounds__(256) void pad_kernel(const float* __restrict__ vol,
                                                  float* __restrict__ ps) {
    const int t = blockIdx.x * 256 + threadIdx.x;
    if (t >= PS_TOT) return;
    const int p  = t / PS_SLAB;
    const int r  = t - p * PS_SLAB;
    const int ci = r / PS_A;
    const int ai = r - ci * PS_A;
    const int c = ci - 1, a = ai - 1;
    float v = 0.0f;
    if (c >= 0 && c < 128 && a >= 0 && a < 128) {
        const float* src = vol + (c << 14) + (p << 7) + a;   // vol[c][p][a]
        v = src[0];
        if (p >= 1) v += src[-128];                          // vol[c][p-1][a]
    }
    ps[t] = v;
}

__device__ __forceinline__ void axis_interval(float base, float slope, float lo, float hi,
                                              float& t0, float& t1) {
    if (fabsf(slope) < 1e-9f) {
        const bool in = (base >= lo && base <= hi);
        t0 = in ? -1e30f : 1e30f;
        t1 = in ?  1e30f : -1e30f;
    } else {
        const float inv = 1.0f / slope;
        const float a = (lo - base) * inv;
        const float b = (hi - base) * inv;
        t0 = fminf(a, b);
        t1 = fmaxf(a, b);
    }
}

__device__ __forceinline__ int wave_imin(int v) {
    #pragma unroll
    for (int o = 32; o; o >>= 1) v = min(v, __shfl_xor(v, o, 64));
    return v;
}
__device__ __forceinline__ int wave_imax(int v) {
    #pragma unroll
    for (int o = 32; o; o >>= 1) v = max(v, __shfl_xor(v, o, 64));
    return v;
}

__global__ __launch_bounds__(128) void proj_fast(
    const float* __restrict__ ps,     // PS [128][131][132]
    const float* __restrict__ poses,  // [50,3]
    const int* __restrict__ idx,      // [10]
    float* __restrict__ out)          // [10,179,179] + [10] tail
{
    const int lane = threadIdx.x & 63;
    const int wid  = threadIdx.x >> 6;      // 2 waves/block
    int gj = blockIdx.x * 64 + lane;        // detector col -> contiguous a
    int gi = blockIdx.y * 2 + wid;          // detector row (wave-uniform)
    const int j = blockIdx.z;

    if (blockIdx.x == 0 && blockIdx.y == 0 && j == 0 && threadIdx.x < NPROJ)
        out[OUT_PROJ + threadIdx.x] = (float)idx[threadIdx.x];

    const bool store_ok = (gi < RES) && (gj < RES);
    gi = min(gi, RES - 1);   // stays wave-uniform
    gj = min(gj, RES - 1);   // dup lanes compute duplicates, store masked

    const int pid = idx[j];
    const float ex = poses[pid * 3 + 0];
    const float ey = poses[pid * 3 + 1];    // [256,384)
    const float ez = poses[pid * 3 + 2];

    const float pdx = (float)gi - 89.5f;
    const float pdz = (float)gj - 89.5f;

    const float inv_ey = 1.0f / ey;
    const float sx = (ex - pdx) * inv_ey;   // wave-uniform
    const float sz = (ez - pdz) * inv_ey;   // per-lane
    const float ddx = pdx - ex, ddz = pdz - ez;
    const float dxw = sqrtf(ddx * ddx + ey * ey + ddz * ddz) * fabsf(inv_ey);
    const float cb = pdx + 63.5f;           // wave-uniform
    const float ab = pdz + 63.5f;

    // Guard trim (conservative superset of nonzero steps), wave-uniform.
    float gc0, gc1, ga0, ga1;
    axis_interval(cb, sx, -1.0f, 128.0f, gc0, gc1);
    axis_interval(ab, sz, -1.0f, 128.0f, ga0, ga1);
    const float q_lo = fmaxf(fmaxf(gc0, ga0), 0.0f);
    const float q_hi = fminf(fminf(gc1, ga1), 127.0f);
    int q0, q1;
    if (q_lo <= q_hi + 0.5f) {
        q0 = max(0, (int)ceilf(q_lo) - 1);
        q1 = min(DVOL, (int)floorf(q_hi) + 2);
    } else { q0 = DVOL; q1 = 0; }           // miss lane: neutral for reduce
    int Q0 = wave_imin(q0);
    int Q1 = wave_imax(q1);
    Q0 = __builtin_amdgcn_readfirstlane(Q0);
    Q1 = __builtin_amdgcn_readfirstlane(Q1);

    float acc = 0.0f;
    int p = Q0;
    float cf = fmaf((float)Q0, sx, cb);
    float af = fmaf((float)Q0, sz, ab);
    const float* slab = ps + Q0 * PS_SLAB;

    // ---- batched main loop: 16 independent loads in flight per wave ----
    for (; p + (BATCH - 1) < Q1; p += BATCH) {
        float tc[BATCH], ta[BATCH];
        float2 r0[BATCH], r1[BATCH];
        #pragma unroll
        for (int k = 0; k < BATCH; ++k) {
            // independent from batch base (no serial chain); clamp to [-1,128]:
            // out-of-guard lanes land on the PS zero border.
            const float cfc = fminf(fmaxf(fmaf((float)k, sx, cf), -1.0f), 128.0f);
            const float afc = fminf(fmaxf(fmaf((float)k, sz, af), -1.0f), 128.0f);
            const float c0f = floorf(cfc);
            const float a0f = floorf(afc);
            tc[k] = cfc - c0f;
            ta[k] = afc - a0f;
            const int c0 = __builtin_amdgcn_readfirstlane((int)c0f);  // uniform
            const int a0 = (int)a0f;
            const float* row = slab + k * PS_SLAB + (c0 + 1) * PS_A + 1;
            r0[k] = *(const float2*)(row + a0);
            r1[k] = *(const float2*)(row + PS_A + a0);
        }
        #pragma unroll
        for (int k = 0; k < BATCH; ++k) {
            const float h0 = fmaf(ta[k], r0[k].y - r0[k].x, r0[k].x);
            const float h1 = fmaf(ta[k], r1[k].y - r1[k].x, r1[k].x);
            acc += fmaf(tc[k], h1 - h0, h0);
        }
        cf += (float)BATCH * sx;
        af += (float)BATCH * sz;
        slab += BATCH * PS_SLAB;
    }
    // ---- remainder ----
    for (; p < Q1; ++p) {
        const float cfc = fminf(fmaxf(cf, -1.0f), 128.0f);
        const float afc = fminf(fmaxf(af, -1.0f), 128.0f);
        const float c0f = floorf(cfc);
        const float a0f = floorf(afc);
        const float tc = cfc - c0f;
        const float ta = afc - a0f;
        const int c0 = __builtin_amdgcn_readfirstlane((int)c0f);
        const int a0 = (int)a0f;
        const float* row = slab + (c0 + 1) * PS_A + 1;
        const float2 r0 = *(const float2*)(row + a0);
        const float2 r1 = *(const float2*)(row + PS_A + a0);
        const float h0 = fmaf(ta, r0.y - r0.x, r0.x);
        const float h1 = fmaf(ta, r1.y - r1.x, r1.x);
        acc += fmaf(tc, h1 - h0, h0);
        cf += sx; af += sz; slab += PS_SLAB;
    }

    if (store_ok) out[j * (RES * RES) + gi * RES + gj] = acc * (0.5f * dxw);
}

// ---------- fallback (R3-proven, used only if ws too small) ----------
__global__ __launch_bounds__(256) void proj_kernel_fb(
    const float* __restrict__ vol, const float* __restrict__ poses,
    const int* __restrict__ idx, float* __restrict__ out)
{
    const int gj = blockIdx.x * 64 + (threadIdx.x & 63);
    const int gi = blockIdx.y * 4 + (threadIdx.x >> 6);
    const int j  = blockIdx.z;
    if (blockIdx.x == 0 && blockIdx.y == 0 && j == 0 && threadIdx.x < NPROJ)
        out[OUT_PROJ + threadIdx.x] = (float)idx[threadIdx.x];
    if (gi >= RES || gj >= RES) return;
    const int pid = idx[j];
    const float ex = poses[pid*3+0], ey = poses[pid*3+1], ez = poses[pid*3+2];
    const float pdx = (float)gi - 89.5f, pdz = (float)gj - 89.5f;
    const float inv_ey = 1.0f / ey;
    const float sx = (ex - pdx) * inv_ey, sz = (ez - pdz) * inv_ey;
    const float ddx = pdx - ex, ddz = pdz - ez;
    const float dxw = sqrtf(ddx*ddx + ey*ey + ddz*ddz) * fabsf(inv_ey);
    const float cb = pdx + 63.5f, ab = pdz + 63.5f;
    float acc = 0.0f;
    for (int p = 0; p < DVOL; ++p) {
        const float cf = fmaf((float)p, sx, cb);
        const float af = fmaf((float)p, sz, ab);
        if (cf >= -1.0f && cf < 128.0f && af >= -1.0f && af < 128.0f) {
            const float c0f = floorf(cf), a0f = floorf(af);
            const float tc = cf - c0f, ta = af - a0f;
            const int c0 = (int)c0f, a0 = (int)a0f;
            const float wc0 = (c0 >= 0)   ? (1.0f - tc) : 0.0f;
            const float wc1 = (c0 <= 126) ? tc          : 0.0f;
            const float wa0 = (a0 >= 0)   ? (1.0f - ta) : 0.0f;
            const float wa1 = (a0 <= 126) ? ta          : 0.0f;
            const int c0c = c0 < 0 ? 0 : c0;
            const int c1c = c0 >= 127 ? 127 : c0 + 1;
            const int a0c = a0 < 0 ? 0 : a0;
            const int a1c = a0 >= 127 ? 127 : a0 + 1;
            const float w00 = wc0*wa0, w01 = wc0*wa1, w10 = wc1*wa0, w11 = wc1*wa1;
            const int b0 = (c0c << 14) + (p << 7);
            const int b1 = (c1c << 14) + (p << 7);
            float s = w00*vol[b0+a0c] + w01*vol[b0+a1c] + w10*vol[b1+a0c] + w11*vol[b1+a1c];
            if (p >= 1)
                s += w00*vol[b0+a0c-128] + w01*vol[b0+a1c-128]
                   + w10*vol[b1+a0c-128] + w11*vol[b1+a1c-128];
            acc += 0.5f * s;
        }
    }
    out[j * (RES * RES) + gi * RES + gj] = acc * dxw;
}

extern "C" void kernel_launch(void* const* d_in, const int* in_sizes, int n_in,
                              void* d_out, int out_size, void* d_ws, size_t ws_size,
                              hipStream_t stream) {
    const float* vol   = (const float*)d_in[0];
    const float* poses = (const float*)d_in[1];
    const int*   idx   = (const int*)d_in[2];
    float* out = (float*)d_out;

    if (ws_size >= (size_t)PS_TOT * sizeof(float)) {
        float* ps = (float*)d_ws;
        pad_kernel<<<PS_TOT / 256, 256, 0, stream>>>(vol, ps);   // PS_TOT % 256 == 0
        dim3 grid(3 /*ceil(179/64)*/, 90 /*ceil(179/2)*/, NPROJ);  // 2700 x 128-thr
        proj_fast<<<grid, 128, 0, stream>>>(ps, poses, idx, out);
    } else {
        dim3 grid(3, 45, NPROJ);
        proj_kernel_fb<<<grid, 256, 0, stream>>>(vol, poses, idx, out);
    }
}

// Round 10
// 101.386 us; speedup vs baseline: 1.2037x; 1.0724x over previous
//
#include <hip/hip_runtime.h>
#include <hip/hip_bf16.h>
#include <stdint.h>

// X-ray forward projection. Volume 128^3 fp32, detector 179x179, 10 views.
// Inputs fp32/int32: I_rec [1,1,128,128,128], poses [50,3], idx [10].
// Output fp32 flat: projections [10,179,179] then idx [10] as float.
//
// Geometry: vol[c][y][a], c = spatial_x+63.5, y index = plane p, a = spatial_z+63.5.
// Sampled y at plane p is exactly p-0.5 => ty=0.5:
//   contribution(p) = 0.5*(bilin(slice p-1) + bilin(slice p)) = 0.5*bilin(PS[p])
// Ray linear in p: c(p)=cb+p*sx, a(p)=ab+p*sz;  weight dxw = dist(Pd,E)/ey.
//
// R10: bf16 ROW-INTERLEAVED PS. IL[p][ci][ai] uint32 = {bf16 PS(row ci+1,col ai)
// <<16 | bf16 PS(row ci,col ai)}, zero-padded borders. ONE uint2 load per step
// yields all 4 bilinear corners (words ai, ai+1). Same 8.8 MB footprint, half
// the bytes/lane, half the loads of R9 (which was VMEM-line + latency bound:
// 46us, VALUBusy 50%, 2 loads x 16B/lane = ~18 L1 lines/step).
// bf16 is exact for the ones-volume (PS in {0,1,2}); <=0.4% rel generally.
// R9's BATCH=8 register batching (VGPR=40 verified) and 128-thr grid kept.

#define DVOL   128
#define RES    179
#define NPROJ  10
#define OUT_PROJ (NPROJ * RES * RES)
#define BATCH  8

#define IL_A   132                    // word cols: ai in [0,132); col a = ai-1
#define IL_C   130                    // word rows: ci in [0,130); row pair (ci, ci+1) of padded grid
#define IL_SLAB (IL_C * IL_A)         // 17160 words per p-slab
#define IL_TOT  (DVOL * IL_SLAB)      // 2,196,480 words = 8.79 MB

__device__ __forceinline__ float psval(const float* __restrict__ vol, int p, int r, int ai) {
    // padded-grid row r -> c = r-1; col ai -> a = ai-1; zero outside [0,128)
    const int c = r - 1, a = ai - 1;
    if (c < 0 || c >= 128 || a < 0 || a >= 128) return 0.0f;
    const float* src = vol + (c << 14) + (p << 7) + a;       // vol[c][p][a]
    float v = src[0];
    if (p >= 1) v += src[-128];                              // vol[c][p-1][a]
    return v;
}

__device__ __forceinline__ uint32_t bfbits(float v) {
    __hip_bfloat16 h = __float2bfloat16(v);
    return (uint32_t)*(unsigned short*)&h;
}

// ---- IL builder: one thread per packed word. IL_TOT % 256 == 0.
__global__ __launch_bounds__(256) void pad_kernel(const float* __restrict__ vol,
                                                  uint32_t* __restrict__ il) {
    const int t = blockIdx.x * 256 + threadIdx.x;
    if (t >= IL_TOT) return;
    const int p  = t / IL_SLAB;
    const int r  = t - p * IL_SLAB;
    const int ci = r / IL_A;
    const int ai = r - ci * IL_A;
    const float lo = psval(vol, p, ci,     ai);   // row c = ci-1
    const float hi = psval(vol, p, ci + 1, ai);   // row c = ci
    il[t] = (bfbits(hi) << 16) | bfbits(lo);
}

__device__ __forceinline__ void axis_interval(float base, float slope, float lo, float hi,
                                              float& t0, float& t1) {
    if (fabsf(slope) < 1e-9f) {
        const bool in = (base >= lo && base <= hi);
        t0 = in ? -1e30f : 1e30f;
        t1 = in ?  1e30f : -1e30f;
    } else {
        const float inv = 1.0f / slope;
        const float a = (lo - base) * inv;
        const float b = (hi - base) * inv;
        t0 = fminf(a, b);
        t1 = fmaxf(a, b);
    }
}

__device__ __forceinline__ int wave_imin(int v) {
    #pragma unroll
    for (int o = 32; o; o >>= 1) v = min(v, __shfl_xor(v, o, 64));
    return v;
}
__device__ __forceinline__ int wave_imax(int v) {
    #pragma unroll
    for (int o = 32; o; o >>= 1) v = max(v, __shfl_xor(v, o, 64));
    return v;
}

__device__ __forceinline__ float asf(uint32_t u) { return __uint_as_float(u); }

__global__ __launch_bounds__(128) void proj_fast(
    const uint32_t* __restrict__ il,  // IL [128][130][132] packed bf16 pairs
    const float* __restrict__ poses,  // [50,3]
    const int* __restrict__ idx,      // [10]
    float* __restrict__ out)          // [10,179,179] + [10] tail
{
    const int lane = threadIdx.x & 63;
    const int wid  = threadIdx.x >> 6;      // 2 waves/block
    int gj = blockIdx.x * 64 + lane;        // detector col -> contiguous a
    int gi = blockIdx.y * 2 + wid;          // detector row (wave-uniform)
    const int j = blockIdx.z;

    if (blockIdx.x == 0 && blockIdx.y == 0 && j == 0 && threadIdx.x < NPROJ)
        out[OUT_PROJ + threadIdx.x] = (float)idx[threadIdx.x];

    const bool store_ok = (gi < RES) && (gj < RES);
    gi = min(gi, RES - 1);   // stays wave-uniform
    gj = min(gj, RES - 1);   // dup lanes compute duplicates, store masked

    const int pid = idx[j];
    const float ex = poses[pid * 3 + 0];
    const float ey = poses[pid * 3 + 1];    // [256,384)
    const float ez = poses[pid * 3 + 2];

    const float pdx = (float)gi - 89.5f;
    const float pdz = (float)gj - 89.5f;

    const float inv_ey = 1.0f / ey;
    const float sx = (ex - pdx) * inv_ey;   // wave-uniform
    const float sz = (ez - pdz) * inv_ey;   // per-lane
    const float ddx = pdx - ex, ddz = pdz - ez;
    const float dxw = sqrtf(ddx * ddx + ey * ey + ddz * ddz) * fabsf(inv_ey);
    const float cb = pdx + 63.5f;           // wave-uniform
    const float ab = pdz + 63.5f;

    // Guard trim (conservative superset of nonzero steps), wave-uniform.
    float gc0, gc1, ga0, ga1;
    axis_interval(cb, sx, -1.0f, 128.0f, gc0, gc1);
    axis_interval(ab, sz, -1.0f, 128.0f, ga0, ga1);
    const float q_lo = fmaxf(fmaxf(gc0, ga0), 0.0f);
    const float q_hi = fminf(fminf(gc1, ga1), 127.0f);
    int q0, q1;
    if (q_lo <= q_hi + 0.5f) {
        q0 = max(0, (int)ceilf(q_lo) - 1);
        q1 = min(DVOL, (int)floorf(q_hi) + 2);
    } else { q0 = DVOL; q1 = 0; }           // miss lane: neutral for reduce
    int Q0 = wave_imin(q0);
    int Q1 = wave_imax(q1);
    Q0 = __builtin_amdgcn_readfirstlane(Q0);
    Q1 = __builtin_amdgcn_readfirstlane(Q1);

    float acc = 0.0f;
    int p = Q0;
    float cf = fmaf((float)Q0, sx, cb);
    float af = fmaf((float)Q0, sz, ab);
    const uint32_t* slab = il + Q0 * IL_SLAB;

    // ---- batched main loop: 8 independent uint2 loads in flight per wave ----
    for (; p + (BATCH - 1) < Q1; p += BATCH) {
        float tc[BATCH], ta[BATCH];
        uint2 w[BATCH];
        #pragma unroll
        for (int k = 0; k < BATCH; ++k) {
            // independent from batch base; clamp to [-1,128]: out-of-guard
            // lanes land on the zero border of IL.
            const float cfc = fminf(fmaxf(fmaf((float)k, sx, cf), -1.0f), 128.0f);
            const float afc = fminf(fmaxf(fmaf((float)k, sz, af), -1.0f), 128.0f);
            const float c0f = floorf(cfc);
            const float a0f = floorf(afc);
            tc[k] = cfc - c0f;
            ta[k] = afc - a0f;
            const int c0 = __builtin_amdgcn_readfirstlane((int)c0f);  // uniform
            const int a0 = (int)a0f;
            // word row ci = c0+1 (rows c0,c0+1); word col ai = a0+1 (cols a0,a0+1)
            const uint32_t* wr = slab + k * IL_SLAB + (c0 + 1) * IL_A + 1;
            w[k] = *(const uint2*)(wr + a0);
        }
        #pragma unroll
        for (int k = 0; k < BATCH; ++k) {
            const float f00 = asf(w[k].x << 16);          // row c0,   col a0
            const float f10 = asf(w[k].x & 0xffff0000u);  // row c0+1, col a0
            const float f01 = asf(w[k].y << 16);          // row c0,   col a0+1
            const float f11 = asf(w[k].y & 0xffff0000u);  // row c0+1, col a0+1
            const float h0 = fmaf(ta[k], f01 - f00, f00);
            const float h1 = fmaf(ta[k], f11 - f10, f10);
            acc += fmaf(tc[k], h1 - h0, h0);
        }
        cf += (float)BATCH * sx;
        af += (float)BATCH * sz;
        slab += BATCH * IL_SLAB;
    }
    // ---- remainder ----
    for (; p < Q1; ++p) {
        const float cfc = fminf(fmaxf(cf, -1.0f), 128.0f);
        const float afc = fminf(fmaxf(af, -1.0f), 128.0f);
        const float c0f = floorf(cfc);
        const float a0f = floorf(afc);
        const float tc = cfc - c0f;
        const float ta = afc - a0f;
        const int c0 = __builtin_amdgcn_readfirstlane((int)c0f);
        const int a0 = (int)a0f;
        const uint32_t* wr = slab + (c0 + 1) * IL_A + 1;
        const uint2 w2 = *(const uint2*)(wr + a0);
        const float f00 = asf(w2.x << 16);
        const float f10 = asf(w2.x & 0xffff0000u);
        const float f01 = asf(w2.y << 16);
        const float f11 = asf(w2.y & 0xffff0000u);
        const float h0 = fmaf(ta, f01 - f00, f00);
        const float h1 = fmaf(ta, f11 - f10, f10);
        acc += fmaf(tc, h1 - h0, h0);
        cf += sx; af += sz; slab += IL_SLAB;
    }

    if (store_ok) out[j * (RES * RES) + gi * RES + gj] = acc * (0.5f * dxw);
}

// ---------- fallback (R3-proven, used only if ws too small) ----------
__global__ __launch_bounds__(256) void proj_kernel_fb(
    const float* __restrict__ vol, const float* __restrict__ poses,
    const int* __restrict__ idx, float* __restrict__ out)
{
    const int gj = blockIdx.x * 64 + (threadIdx.x & 63);
    const int gi = blockIdx.y * 4 + (threadIdx.x >> 6);
    const int j  = blockIdx.z;
    if (blockIdx.x == 0 && blockIdx.y == 0 && j == 0 && threadIdx.x < NPROJ)
        out[OUT_PROJ + threadIdx.x] = (float)idx[threadIdx.x];
    if (gi >= RES || gj >= RES) return;
    const int pid = idx[j];
    const float ex = poses[pid*3+0], ey = poses[pid*3+1], ez = poses[pid*3+2];
    const float pdx = (float)gi - 89.5f, pdz = (float)gj - 89.5f;
    const float inv_ey = 1.0f / ey;
    const float sx = (ex - pdx) * inv_ey, sz = (ez - pdz) * inv_ey;
    const float ddx = pdx - ex, ddz = pdz - ez;
    const float dxw = sqrtf(ddx*ddx + ey*ey + ddz*ddz) * fabsf(inv_ey);
    const float cb = pdx + 63.5f, ab = pdz + 63.5f;
    float acc = 0.0f;
    for (int p = 0; p < DVOL; ++p) {
        const float cf = fmaf((float)p, sx, cb);
        const float af = fmaf((float)p, sz, ab);
        if (cf >= -1.0f && cf < 128.0f && af >= -1.0f && af < 128.0f) {
            const float c0f = floorf(cf), a0f = floorf(af);
            const float tc = cf - c0f, ta = af - a0f;
            const int c0 = (int)c0f, a0 = (int)a0f;
            const float wc0 = (c0 >= 0)   ? (1.0f - tc) : 0.0f;
            const float wc1 = (c0 <= 126) ? tc          : 0.0f;
            const float wa0 = (a0 >= 0)   ? (1.0f - ta) : 0.0f;
            const float wa1 = (a0 <= 126) ? ta          : 0.0f;
            const int c0c = c0 < 0 ? 0 : c0;
            const int c1c = c0 >= 127 ? 127 : c0 + 1;
            const int a0c = a0 < 0 ? 0 : a0;
            const int a1c = a0 >= 127 ? 127 : a0 + 1;
            const float w00 = wc0*wa0, w01 = wc0*wa1, w10 = wc1*wa0, w11 = wc1*wa1;
            const int b0 = (c0c << 14) + (p << 7);
            const int b1 = (c1c << 14) + (p << 7);
            float s = w00*vol[b0+a0c] + w01*vol[b0+a1c] + w10*vol[b1+a0c] + w11*vol[b1+a1c];
            if (p >= 1)
                s += w00*vol[b0+a0c-128] + w01*vol[b0+a1c-128]
                   + w10*vol[b1+a0c-128] + w11*vol[b1+a1c-128];
            acc += 0.5f * s;
        }
    }
    out[j * (RES * RES) + gi * RES + gj] = acc * dxw;
}

extern "C" void kernel_launch(void* const* d_in, const int* in_sizes, int n_in,
                              void* d_out, int out_size, void* d_ws, size_t ws_size,
                              hipStream_t stream) {
    const float* vol   = (const float*)d_in[0];
    const float* poses = (const float*)d_in[1];
    const int*   idx   = (const int*)d_in[2];
    float* out = (float*)d_out;

    if (ws_size >= (size_t)IL_TOT * sizeof(uint32_t)) {
        uint32_t* ilbuf = (uint32_t*)d_ws;
        pad_kernel<<<IL_TOT / 256, 256, 0, stream>>>(vol, ilbuf);  // IL_TOT % 256 == 0
        dim3 grid(3 /*ceil(179/64)*/, 90 /*ceil(179/2)*/, NPROJ);  // 2700 x 128-thr
        proj_fast<<<grid, 128, 0, stream>>>(ilbuf, poses, idx, out);
    } else {
        dim3 grid(3, 45, NPROJ);
        proj_kernel_fb<<<grid, 256, 0, stream>>>(vol, poses, idx, out);
    }
}